// Round 8
// baseline (158.080 us; speedup 1.0000x reference)
//
#include <hip/hip_runtime.h>

#define DIM 512
#define BATCH 65536
#define BM 64
#define THREADS 512

typedef float f32x4 __attribute__((ext_vector_type(4)));
typedef float f32x16 __attribute__((ext_vector_type(16)));
typedef __bf16 bf16x8 __attribute__((ext_vector_type(8)));

__device__ __forceinline__ unsigned f2bf(float f) {
    unsigned u = __float_as_uint(f);
    return (u + 0x7FFFu + ((u >> 16) & 1u)) >> 16;
}

// Sf in MFMA-B-fragment order: Sf[((k0*16 + np)*64 + lane)*8 + j]
//   = bf16( A[n][k] + A[k][n] ),  n = np*32 + (lane&31),  k = k0*16 + (lane>>5)*8 + j
__global__ void prep_Sfrag(const float* __restrict__ A, unsigned short* __restrict__ Sf) {
    int idx = blockIdx.x * 256 + threadIdx.x;    // 0..32767 : (k0, np, lane)
    int lane = idx & 63;
    int np   = (idx >> 6) & 15;
    int k0   = idx >> 10;
    int n     = np * 32 + (lane & 31);
    int kbase = k0 * 16 + (lane >> 5) * 8;
    unsigned short tmp[8];
    #pragma unroll
    for (int j = 0; j < 8; ++j) {
        int k = kbase + j;
        tmp[j] = (unsigned short)f2bf(A[n * DIM + k] + A[k * DIM + n]);
    }
    *(uint4*)(Sf + (size_t)idx * 8) = *(const uint4*)tmp;
}

// out[b][0:512] = p[b] + q[b].S ; out[b][512:1024] = q[b]
// BM=64: each wave register-blocks 2 A-frags (rows) x 2 B-panels (cols),
// so every Sf fragment read from L2 feeds 2 MFMAs (halves Sf L2 traffic).
__global__ __launch_bounds__(THREADS, 4)
void gemm_kernel(const float* __restrict__ pq,
                 const unsigned short* __restrict__ Sf,
                 float* __restrict__ out) {
    __shared__ unsigned short qs[BM * DIM];   // 64 KB: bf16 q tile, then f32 acc scratch
    const int rb  = blockIdx.x * BM;
    const int tid = threadIdx.x;
    const int wid  = tid >> 6;
    const int lane = tid & 63;
    const int row  = lane & 31;
    const int khalf = lane >> 5;

    // ---- Stage q tile -> LDS (bf16, swizzled); fuse q -> out[:,512:] passthrough
    #pragma unroll
    for (int i = 0; i < 16; ++i) {
        int flat = (tid + i * THREADS) * 4;
        int r = flat >> 9, c = flat & 511;
        size_t g = (size_t)(rb + r) * 1024 + 512 + c;
        f32x4 v = __builtin_nontemporal_load((const f32x4*)(pq + g));
        __builtin_nontemporal_store(v, (f32x4*)(out + g));
        unsigned lo = f2bf(v.x) | (f2bf(v.y) << 16);
        unsigned hi = f2bf(v.z) | (f2bf(v.w) << 16);
        int bo = (c * 2) ^ ((r & 15) << 4);
        *(uint2*)((char*)qs + r * 1024 + bo) = make_uint2(lo, hi);
    }
    __syncthreads();

    // ---- k-loop: 2x2 register blocking, depth-2 pipeline on the B (L2) loads
    const unsigned short* Sfp = Sf + ((size_t)(wid * 2) * 64 + lane) * 8;
    f32x16 acc00 = {}, acc01 = {}, acc10 = {}, acc11 = {};
    bf16x8 b0_c = *(const bf16x8*)(Sfp);
    bf16x8 b1_c = *(const bf16x8*)(Sfp + 512);
    #pragma unroll
    for (int k0 = 0; k0 < 32; ++k0) {
        bf16x8 b0_n, b1_n;
        if (k0 < 31) {
            b0_n = *(const bf16x8*)(Sfp + (size_t)(k0 + 1) * 8192);
            b1_n = *(const bf16x8*)(Sfp + (size_t)(k0 + 1) * 8192 + 512);
        }
        int bo = (k0 * 32 + khalf * 16) ^ ((row & 15) << 4);
        bf16x8 a0 = *(const bf16x8*)((const char*)qs + row * 1024 + bo);
        bf16x8 a1 = *(const bf16x8*)((const char*)qs + (32 + row) * 1024 + bo);
        acc00 = __builtin_amdgcn_mfma_f32_32x32x16_bf16(a0, b0_c, acc00, 0, 0, 0);
        acc01 = __builtin_amdgcn_mfma_f32_32x32x16_bf16(a0, b1_c, acc01, 0, 0, 0);
        acc10 = __builtin_amdgcn_mfma_f32_32x32x16_bf16(a1, b0_c, acc10, 0, 0, 0);
        acc11 = __builtin_amdgcn_mfma_f32_32x32x16_bf16(a1, b1_c, acc11, 0, 0, 0);
        if (k0 < 31) { b0_c = b0_n; b1_c = b1_n; }
    }

    // ---- Epilogue: LDS round-trip, 2 passes over panels; p read at store time.
    // sc[64][256] f32 (64 KB = qs): rows 0..63, col = wid*32 + (lane&31).
    float* sc = (float*)qs;
    __syncthreads();                       // all waves done reading qs
    #pragma unroll
    for (int pass = 0; pass < 2; ++pass) {
        const f32x16& aT = pass ? acc01 : acc00;   // top slab (rows 0..31)
        const f32x16& aB = pass ? acc11 : acc10;   // bottom slab (rows 32..63)
        #pragma unroll
        for (int reg = 0; reg < 16; ++reg) {
            int r = (reg & 3) + 8 * (reg >> 2) + 4 * khalf;
            sc[r * 256 + wid * 32 + row]        = aT[reg];   // 2-way bank alias: free
            sc[(32 + r) * 256 + wid * 32 + row] = aB[reg];
        }
        __syncthreads();
        #pragma unroll
        for (int j = 0; j < 8; ++j) {
            int c  = tid + j * THREADS;                // 0..4095
            int r  = c >> 6, cc = c & 63;
            int gcol = (cc >> 3) * 64 + pass * 32 + (cc & 7) * 4;
            size_t g = (size_t)(rb + r) * 1024 + gcol;
            f32x4 v  = *(const f32x4*)(sc + r * 256 + cc * 4);
            f32x4 pv = __builtin_nontemporal_load((const f32x4*)(pq + g));
            __builtin_nontemporal_store(pv + v, (f32x4*)(out + g));
        }
        if (pass == 0) __syncthreads();
    }
}

extern "C" void kernel_launch(void* const* d_in, const int* in_sizes, int n_in,
                              void* d_out, int out_size, void* d_ws, size_t ws_size,
                              hipStream_t stream) {
    const float* pq = (const float*)d_in[0];
    const float* A  = (const float*)d_in[1];
    float* out = (float*)d_out;
    unsigned short* Sf = (unsigned short*)d_ws;   // 512 KB fragment-ordered S

    prep_Sfrag<<<128, 256, 0, stream>>>(A, Sf);
    gemm_kernel<<<BATCH / BM, THREADS, 0, stream>>>(pq, Sf, out);
}

// Round 9
// 131.664 us; speedup vs baseline: 1.2006x; 1.2006x over previous
//
#include <hip/hip_runtime.h>

#define DIM 512
#define BATCH 65536
#define BM 32
#define THREADS 512
#define TILES 4
#define NBLK (BATCH / (BM * TILES))   // 512 blocks

typedef float f32x4 __attribute__((ext_vector_type(4)));
typedef float f32x16 __attribute__((ext_vector_type(16)));
typedef __bf16 bf16x8 __attribute__((ext_vector_type(8)));

__device__ __forceinline__ unsigned f2bf(float f) {
    unsigned u = __float_as_uint(f);
    return (u + 0x7FFFu + ((u >> 16) & 1u)) >> 16;
}

// Sf in MFMA-B-fragment order: Sf[((k0*16 + np)*64 + lane)*8 + j]
//   = bf16( A[n][k] + A[k][n] ),  n = np*32 + (lane&31),  k = k0*16 + (lane>>5)*8 + j
__global__ void prep_Sfrag(const float* __restrict__ A, unsigned short* __restrict__ Sf) {
    int idx = blockIdx.x * 256 + threadIdx.x;    // 0..32767 : (k0, np, lane)
    int lane = idx & 63;
    int np   = (idx >> 6) & 15;
    int k0   = idx >> 10;
    int n     = np * 32 + (lane & 31);
    int kbase = k0 * 16 + (lane >> 5) * 8;
    unsigned short tmp[8];
    #pragma unroll
    for (int j = 0; j < 8; ++j) {
        int k = kbase + j;
        tmp[j] = (unsigned short)f2bf(A[n * DIM + k] + A[k * DIM + n]);
    }
    *(uint4*)(Sf + (size_t)idx * 8) = *(const uint4*)tmp;
}

// out[b][0:512] = p[b] + q[b].S ; out[b][512:1024] = q[b]
// Persistent 4-tile blocks; each tile's K split in 2 halves, double-buffered:
// phase = (tile, half). Per phase: issue loads(ph+1) -> k-half(ph) -> write-back(ph+1).
__global__ __launch_bounds__(THREADS, 4)
void gemm_kernel(const float* __restrict__ pq,
                 const unsigned short* __restrict__ Sf,
                 float* __restrict__ out) {
    __shared__ __align__(16) unsigned short qh[2][BM * 256];  // 2 x 16 KB bf16 half-K
    __shared__ float sc[BM * 256];                            // 32 KB epilogue scratch
    const int tid  = threadIdx.x;
    const int wid  = tid >> 6;
    const int lane = tid & 63;
    const int row  = lane & 31;
    const int khalf = lane >> 5;
    const int rb = blockIdx.x * (BM * TILES);
    const unsigned short* Sfp = Sf + ((size_t)(wid * 2) * 64 + lane) * 8;
    const int col0 = wid * 64 + row;
    (void)col0;

    f32x4 stg[4];   // staged q for the next phase (2 slots x 2 f32x4)

    // slot geometry: slot = i*THREADS+tid (i=0,1); r = slot>>5 (32 chunks/row),
    // c8 = slot&31 -> global float col = half*256 + c8*8;
    // LDS byte = r*512 + (c8*16 ^ ((r&7)<<4))   [same XOR as the k-loop read]
    auto issue_loads = [&](int ph) {
        int tile = ph >> 1, half = ph & 1;
        #pragma unroll
        for (int i = 0; i < 2; ++i) {
            int slot = i * THREADS + tid;
            int r = slot >> 5, c8 = slot & 31;
            size_t g = (size_t)(rb + tile * BM + r) * 1024 + 512 + half * 256 + c8 * 8;
            stg[2*i]   = __builtin_nontemporal_load((const f32x4*)(pq + g));
            stg[2*i+1] = __builtin_nontemporal_load((const f32x4*)(pq + g + 4));
        }
    };
    auto write_back = [&](int ph) {
        int tile = ph >> 1, half = ph & 1;
        unsigned short* dst = qh[ph & 1];
        #pragma unroll
        for (int i = 0; i < 2; ++i) {
            int slot = i * THREADS + tid;
            int r = slot >> 5, c8 = slot & 31;
            size_t g = (size_t)(rb + tile * BM + r) * 1024 + 512 + half * 256 + c8 * 8;
            __builtin_nontemporal_store(stg[2*i],   (f32x4*)(out + g));     // q passthrough
            __builtin_nontemporal_store(stg[2*i+1], (f32x4*)(out + g + 4));
            unsigned u0 = f2bf(stg[2*i].x)   | (f2bf(stg[2*i].y)   << 16);
            unsigned u1 = f2bf(stg[2*i].z)   | (f2bf(stg[2*i].w)   << 16);
            unsigned u2 = f2bf(stg[2*i+1].x) | (f2bf(stg[2*i+1].y) << 16);
            unsigned u3 = f2bf(stg[2*i+1].z) | (f2bf(stg[2*i+1].w) << 16);
            int b = r * 512 + ((c8 * 16) ^ ((r & 7) << 4));
            *(uint4*)((char*)dst + b) = make_uint4(u0, u1, u2, u3);
        }
    };
    auto khalf_loop = [&](int ph, f32x16& acc0, f32x16& acc1) {
        int half = ph & 1;
        const unsigned short* buf = qh[ph & 1];
        const unsigned short* sp = Sfp + (size_t)(half * 16) * 8192;
        bf16x8 b0_c = *(const bf16x8*)(sp);
        bf16x8 b1_c = *(const bf16x8*)(sp + 512);
        #pragma unroll
        for (int k = 0; k < 16; ++k) {
            bf16x8 b0_n, b1_n;
            if (k < 15) {
                b0_n = *(const bf16x8*)(sp + (size_t)(k + 1) * 8192);
                b1_n = *(const bf16x8*)(sp + (size_t)(k + 1) * 8192 + 512);
            }
            int b = row * 512 + ((k * 32 + khalf * 16) ^ ((row & 7) << 4));
            bf16x8 a = *(const bf16x8*)((const char*)buf + b);
            acc0 = __builtin_amdgcn_mfma_f32_32x32x16_bf16(a, b0_c, acc0, 0, 0, 0);
            acc1 = __builtin_amdgcn_mfma_f32_32x32x16_bf16(a, b1_c, acc1, 0, 0, 0);
            if (k < 15) { b0_c = b0_n; b1_c = b1_n; }
        }
    };
    auto epilogue = [&](int tile, const f32x16& acc0, const f32x16& acc1) {
        int tb = rb + tile * BM;
        #pragma unroll
        for (int pass = 0; pass < 2; ++pass) {
            const f32x16& ac = pass ? acc1 : acc0;
            #pragma unroll
            for (int reg = 0; reg < 16; ++reg) {
                int r = (reg & 3) + 8 * (reg >> 2) + 4 * khalf;
                sc[r * 256 + wid * 32 + row] = ac[reg];   // 2-way bank alias: free
            }
            __syncthreads();
            #pragma unroll
            for (int j = 0; j < 4; ++j) {
                int c = tid + j * 512;
                int r = c >> 6, cc = c & 63;
                int gcol = (cc >> 3) * 64 + (cc & 7) * 4 + pass * 32;
                size_t g = (size_t)(tb + r) * 1024 + gcol;
                f32x4 v  = *(const f32x4*)(sc + r * 256 + cc * 4);
                f32x4 pv = __builtin_nontemporal_load((const f32x4*)(pq + g));
                __builtin_nontemporal_store(pv + v, (f32x4*)(out + g));
            }
            __syncthreads();
        }
    };

    f32x16 acc0, acc1;
    // prologue: phase 0 synchronous
    issue_loads(0);
    write_back(0);
    __syncthreads();

    for (int ph = 0; ph < 2 * TILES; ++ph) {
        if ((ph & 1) == 0) { acc0 = f32x16{}; acc1 = f32x16{}; }
        if (ph + 1 < 2 * TILES) issue_loads(ph + 1);     // in flight across k-half
        khalf_loop(ph, acc0, acc1);
        if (ph + 1 < 2 * TILES) write_back(ph + 1);      // passthrough + LDS fill
        __syncthreads();
        if (ph & 1) epilogue(ph >> 1, acc0, acc1);
    }
}

extern "C" void kernel_launch(void* const* d_in, const int* in_sizes, int n_in,
                              void* d_out, int out_size, void* d_ws, size_t ws_size,
                              hipStream_t stream) {
    const float* pq = (const float*)d_in[0];
    const float* A  = (const float*)d_in[1];
    float* out = (float*)d_out;
    unsigned short* Sf = (unsigned short*)d_ws;   // 512 KB fragment-ordered S

    prep_Sfrag<<<128, 256, 0, stream>>>(A, Sf);
    gemm_kernel<<<NBLK, THREADS, 0, stream>>>(pq, Sf, out);
}